// Round 12
// baseline (143.973 us; speedup 1.0000x reference)
//
#include <hip/hip_runtime.h>

// Multi-Scale Deformable Attention forward, fp32.
//   value:  (B=2, Len=21760, nH=8, D=32) fp32
//   loc:    (B, Q=21760, nH, L=4, P=4, 2) fp32
//   attw:   (B, Q, nH, L, P) fp32
//   out:    (B, Q, nH*D=256) fp32
// Levels: (128,128),(64,64),(32,32),(16,16), starts 0,16384,20480,21504.
//
// R7 skeleton VERBATIM (proven: 140 us, VGPR=80, FETCH 86 MB, no faults):
//  * R5 XCD pinning: one (b,h) pair per block, blockIdx%8 -> XCD; each
//    XCD's 4-MB L2 holds its head's 2.78-MB value slice.
//  * 16-deep asm-volatile gather batch per level, single vmcnt(0) +
//    sched_barrier drain, launch_bounds(.,3).
// R12 change: ONE WAVE PER BLOCK (64 threads, 8 queries/block). R7's
// occupancy read 26% (~2 blocks/CU) despite VGPR=80 allowing 24 waves/CU
// -> residency appears block-granular. Wave-sized blocks multiply
// resident waves without touching the fault-prone asm region.

namespace {
constexpr int kB    = 2;
constexpr int kQ    = 21760;
constexpr int kHd   = 8;
constexpr int kD    = 32;
constexpr int kLen  = 21760;
constexpr int kRow  = kHd * kD;            // 256 floats per spatial position
constexpr int kQBlk = 8;                   // queries per (64-thread) block
constexpr int kBlksPerPair = kQ / kQBlk;   // 2720
}

typedef float f32x4 __attribute__((ext_vector_type(4)));

__global__ __launch_bounds__(64, 3) void msda_fwd(
    const float* __restrict__ value,
    const float* __restrict__ loc,
    const float* __restrict__ attw,
    float* __restrict__ out)
{
    // blockIdx -> (xcd, k); XCD x runs pair (b=0,h=x) then (b=1,h=x).
    const int i    = blockIdx.x;
    const int xcd  = i & 7;
    const int k    = i >> 3;
    const int b    = (k >= kBlksPerPair) ? 1 : 0;
    const int j    = k - b * kBlksPerPair;
    const int h    = xcd;

    const int qi   = threadIdx.x >> 3;     // 0..7
    const int sub  = threadIdx.x & 7;      // channel float4 slot
    const int q    = j * kQBlk + qi;
    const int g    = (b * kQ + q) * kHd + h;

    const float4* lp4 = (const float4*)(loc  + (size_t)g * 32);
    const float4* ap4 = (const float4*)(attw + (size_t)g * 16);
    // 32-bit byte offset of this thread's channel slice within `value`
    const int thrbase = ((b * kLen * kRow) + h * kD + sub * 4) * 4;
    const char* vbase = (const char*)value;

    f32x4 acc = {0.f, 0.f, 0.f, 0.f};

    constexpr int Hs[4] = {128, 64, 32, 16};
    constexpr int Ws[4] = {128, 64, 32, 16};
    constexpr int Ss[4] = {0, 16384, 20480, 21504};

    #pragma unroll
    for (int l = 0; l < 4; ++l) {
        const int W = Ws[l];
        const int H = Hs[l];
        const int base = thrbase + (Ss[l] << 10);   // S * kRow * 4 bytes

        const float4 lc0 = lp4[2 * l];
        const float4 lc1 = lp4[2 * l + 1];
        const float4 av  = ap4[l];

        const float lx[4] = {lc0.x, lc0.z, lc1.x, lc1.z};
        const float ly[4] = {lc0.y, lc0.w, lc1.y, lc1.w};
        const float aa[4] = {av.x,  av.y,  av.z,  av.w};

        int   offs[16];
        float ws[16];

        #pragma unroll
        for (int p = 0; p < 4; ++p) {
            // grid_sample(align_corners=False): x = loc_x * W - 0.5
            const float x = fmaf(lx[p], (float)W, -0.5f);
            const float y = fmaf(ly[p], (float)H, -0.5f);
            const float x0f = floorf(x);
            const float y0f = floorf(y);
            const float fx = x - x0f;
            const float fy = y - y0f;
            const int   x0 = (int)x0f;
            const int   y0 = (int)y0f;
            const float a  = aa[p];

            const bool vx0 = (unsigned)x0       < (unsigned)W;
            const bool vx1 = (unsigned)(x0 + 1) < (unsigned)W;
            const bool vy0 = (unsigned)y0       < (unsigned)H;
            const bool vy1 = (unsigned)(y0 + 1) < (unsigned)H;

            const int xc0 = min(max(x0, 0),     W - 1);
            const int xc1 = min(max(x0 + 1, 0), W - 1);
            const int yc0 = min(max(y0, 0),     H - 1);
            const int yc1 = min(max(y0 + 1, 0), H - 1);

            const float w00 = a * (1.f - fx) * (1.f - fy);
            const float w01 = a * fx * (1.f - fy);
            const float w10 = a * (1.f - fx) * fy;
            const float w11 = a * fx * fy;

            ws[p * 4 + 0] = (vy0 && vx0) ? w00 : 0.f;
            ws[p * 4 + 1] = (vy0 && vx1) ? w01 : 0.f;
            ws[p * 4 + 2] = (vy1 && vx0) ? w10 : 0.f;
            ws[p * 4 + 3] = (vy1 && vx1) ? w11 : 0.f;

            const int r0 = yc0 * W;   // W is power of two -> shift
            const int r1 = yc1 * W;
            offs[p * 4 + 0] = base + ((r0 + xc0) << 10);
            offs[p * 4 + 1] = base + ((r0 + xc1) << 10);
            offs[p * 4 + 2] = base + ((r1 + xc0) << 10);
            offs[p * 4 + 3] = base + ((r1 + xc1) << 10);
        }

        // Issue all 16 gathers back-to-back; volatile asm pins issue order.
        f32x4 tv[16];
        #pragma unroll
        for (int t16 = 0; t16 < 16; ++t16) {
            const void* p = vbase + offs[t16];
            asm volatile("global_load_dwordx4 %0, %1, off"
                         : "=v"(tv[t16]) : "v"(p) : "memory");
        }
        asm volatile("s_waitcnt vmcnt(0)" ::: "memory");
        __builtin_amdgcn_sched_barrier(0);   // rule #18: keep FMAs below wait

        #pragma unroll
        for (int t16 = 0; t16 < 16; ++t16) {
            acc.x = fmaf(ws[t16], tv[t16].x, acc.x);
            acc.y = fmaf(ws[t16], tv[t16].y, acc.y);
            acc.z = fmaf(ws[t16], tv[t16].z, acc.z);
            acc.w = fmaf(ws[t16], tv[t16].w, acc.w);
        }
    }

    float4 r;
    r.x = acc.x; r.y = acc.y; r.z = acc.z; r.w = acc.w;
    *(float4*)(out + ((size_t)(b * kQ + q)) * kRow + h * kD + sub * 4) = r;
}

extern "C" void kernel_launch(void* const* d_in, const int* in_sizes, int n_in,
                              void* d_out, int out_size, void* d_ws, size_t ws_size,
                              hipStream_t stream) {
    const float* value = (const float*)d_in[0];
    const float* loc   = (const float*)d_in[3];
    const float* attw  = (const float*)d_in[4];
    float* out = (float*)d_out;

    const int grid = kB * kHd * kBlksPerPair;   // 16 pairs * 2720 = 43520
    msda_fwd<<<grid, 64, 0, stream>>>(value, loc, attw, out);
}

// Round 13
// 133.056 us; speedup vs baseline: 1.0820x; 1.0820x over previous
//
#include <hip/hip_runtime.h>

// Multi-Scale Deformable Attention forward, fp32.
//   value:  (B=2, Len=21760, nH=8, D=32) fp32
//   loc:    (B, Q=21760, nH, L=4, P=4, 2) fp32
//   attw:   (B, Q, nH, L, P) fp32
//   out:    (B, Q, nH*D=256) fp32
// Levels: (128,128),(64,64),(32,32),(16,16), starts 0,16384,20480,21504.
//
// R13: R5 proven no-asm structure (153 us) + XCD pinning + NEW: level-3
// staged in LDS. Rationale: R5 (2 loads in flight, occ 61%) and R7/R12
// (16 in flight, occ 27%) all land ~175-192 us rocprof -> shared L2
// random-64B throughput ceiling (~16 TB/s effective on 44.6M segments).
// Level 3 slice per (b,h) = 256 px * 128 B = 32 KB -> serve its 25% of
// taps from LDS, removing them from L2 entirely. No inline asm (every
// asm-region deviation faulted: R6/R8/R9/R10/R11).

namespace {
constexpr int kB    = 2;
constexpr int kQ    = 21760;
constexpr int kHd   = 8;
constexpr int kD    = 32;
constexpr int kLen  = 21760;
constexpr int kRow  = kHd * kD;            // 256 floats per spatial position
constexpr int kQBlk = 32;                  // queries per block
constexpr int kBlksPerPair = kQ / kQBlk;   // 680
constexpr int kS3   = 21504;               // level-3 start pixel
}

__device__ __forceinline__ void fma4(float4& a, float w, const float4 v) {
    a.x = fmaf(w, v.x, a.x);
    a.y = fmaf(w, v.y, a.y);
    a.z = fmaf(w, v.z, a.z);
    a.w = fmaf(w, v.w, a.w);
}

__global__ __launch_bounds__(256, 4) void msda_fwd(
    const float* __restrict__ value,
    const float* __restrict__ loc,
    const float* __restrict__ attw,
    float* __restrict__ out)
{
    // blockIdx -> (xcd, k); XCD x runs pair (b=0,h=x) then (b=1,h=x).
    const int i    = blockIdx.x;
    const int xcd  = i & 7;
    const int k    = i >> 3;
    const int b    = (k >= kBlksPerPair) ? 1 : 0;
    const int j    = k - b * kBlksPerPair;
    const int h    = xcd;

    // ---- Preload this pair's level-3 slice (256 px * 32 ch) into LDS ----
    __shared__ float lv3[256 * kD];        // 32 KB
    {
        const float* src = value + ((size_t)(b * kLen + kS3)) * kRow + h * kD;
        float4* dst = (float4*)lv3;
        #pragma unroll
        for (int r = 0; r < 8; ++r) {
            const int idx  = r * 256 + threadIdx.x;   // 0..2047 float4s
            const int pix  = idx >> 3;
            const int quad = idx & 7;
            dst[idx] = *(const float4*)(src + (size_t)pix * kRow + quad * 4);
        }
    }
    __syncthreads();

    const int qi   = threadIdx.x >> 3;     // 0..31
    const int sub  = threadIdx.x & 7;      // channel float4 slot
    const int q    = j * kQBlk + qi;
    const int g    = (b * kQ + q) * kHd + h;

    const float4* lp4 = (const float4*)(loc  + (size_t)g * 32);
    const float4* ap4 = (const float4*)(attw + (size_t)g * 16);
    const float*  vb  = value + (size_t)b * kLen * kRow + h * kD + sub * 4;

    float4 acc = make_float4(0.f, 0.f, 0.f, 0.f);

    constexpr int Hs[3] = {128, 64, 32};
    constexpr int Ws[3] = {128, 64, 32};
    constexpr int Ss[3] = {0, 16384, 20480};

    // ---- Levels 0..2: global gather (L2-resident via XCD pinning) ----
    #pragma unroll
    for (int l = 0; l < 3; ++l) {
        const int W = Ws[l];
        const int H = Hs[l];
        const int S = Ss[l];

        const float4 lc0 = lp4[2 * l];
        const float4 lc1 = lp4[2 * l + 1];
        const float4 av  = ap4[l];

        const float lx[4] = {lc0.x, lc0.z, lc1.x, lc1.z};
        const float ly[4] = {lc0.y, lc0.w, lc1.y, lc1.w};
        const float aa[4] = {av.x,  av.y,  av.z,  av.w};

        #pragma unroll
        for (int p = 0; p < 4; ++p) {
            // grid_sample(align_corners=False): x = loc_x * W - 0.5
            const float x = fmaf(lx[p], (float)W, -0.5f);
            const float y = fmaf(ly[p], (float)H, -0.5f);
            const float x0f = floorf(x);
            const float y0f = floorf(y);
            const float fx = x - x0f;
            const float fy = y - y0f;
            const int   x0 = (int)x0f;
            const int   y0 = (int)y0f;
            const float a  = aa[p];

            const bool vx0 = (unsigned)x0       < (unsigned)W;
            const bool vx1 = (unsigned)(x0 + 1) < (unsigned)W;
            const bool vy0 = (unsigned)y0       < (unsigned)H;
            const bool vy1 = (unsigned)(y0 + 1) < (unsigned)H;

            const int xc0 = min(max(x0, 0),     W - 1);
            const int xc1 = min(max(x0 + 1, 0), W - 1);
            const int yc0 = min(max(y0, 0),     H - 1);
            const int yc1 = min(max(y0 + 1, 0), H - 1);

            float w00 = a * (1.f - fx) * (1.f - fy);
            float w01 = a * fx * (1.f - fy);
            float w10 = a * (1.f - fx) * fy;
            float w11 = a * fx * fy;
            w00 = (vy0 && vx0) ? w00 : 0.f;
            w01 = (vy0 && vx1) ? w01 : 0.f;
            w10 = (vy1 && vx0) ? w10 : 0.f;
            w11 = (vy1 && vx1) ? w11 : 0.f;

            const int r0 = (S + yc0 * W) * kRow;
            const int r1 = (S + yc1 * W) * kRow;
            const float4 v00 = *(const float4*)(vb + r0 + xc0 * kRow);
            const float4 v01 = *(const float4*)(vb + r0 + xc1 * kRow);
            const float4 v10 = *(const float4*)(vb + r1 + xc0 * kRow);
            const float4 v11 = *(const float4*)(vb + r1 + xc1 * kRow);

            fma4(acc, w00, v00);
            fma4(acc, w01, v01);
            fma4(acc, w10, v10);
            fma4(acc, w11, v11);
        }
    }

    // ---- Level 3: serve from LDS ----
    {
        constexpr int W = 16, H = 16;
        const float4 lc0 = lp4[6];
        const float4 lc1 = lp4[7];
        const float4 av  = ap4[3];

        const float lx[4] = {lc0.x, lc0.z, lc1.x, lc1.z};
        const float ly[4] = {lc0.y, lc0.w, lc1.y, lc1.w};
        const float aa[4] = {av.x,  av.y,  av.z,  av.w};

        #pragma unroll
        for (int p = 0; p < 4; ++p) {
            const float x = fmaf(lx[p], (float)W, -0.5f);
            const float y = fmaf(ly[p], (float)H, -0.5f);
            const float x0f = floorf(x);
            const float y0f = floorf(y);
            const float fx = x - x0f;
            const float fy = y - y0f;
            const int   x0 = (int)x0f;
            const int   y0 = (int)y0f;
            const float a  = aa[p];

            const bool vx0 = (unsigned)x0       < (unsigned)W;
            const bool vx1 = (unsigned)(x0 + 1) < (unsigned)W;
            const bool vy0 = (unsigned)y0       < (unsigned)H;
            const bool vy1 = (unsigned)(y0 + 1) < (unsigned)H;

            const int xc0 = min(max(x0, 0),     W - 1);
            const int xc1 = min(max(x0 + 1, 0), W - 1);
            const int yc0 = min(max(y0, 0),     H - 1);
            const int yc1 = min(max(y0 + 1, 0), H - 1);

            float w00 = a * (1.f - fx) * (1.f - fy);
            float w01 = a * fx * (1.f - fy);
            float w10 = a * (1.f - fx) * fy;
            float w11 = a * fx * fy;
            w00 = (vy0 && vx0) ? w00 : 0.f;
            w01 = (vy0 && vx1) ? w01 : 0.f;
            w10 = (vy1 && vx0) ? w10 : 0.f;
            w11 = (vy1 && vx1) ? w11 : 0.f;

            const float* lbase = lv3 + sub * 4;
            const float4 v00 = *(const float4*)(lbase + (yc0 * W + xc0) * kD);
            const float4 v01 = *(const float4*)(lbase + (yc0 * W + xc1) * kD);
            const float4 v10 = *(const float4*)(lbase + (yc1 * W + xc0) * kD);
            const float4 v11 = *(const float4*)(lbase + (yc1 * W + xc1) * kD);

            fma4(acc, w00, v00);
            fma4(acc, w01, v01);
            fma4(acc, w10, v10);
            fma4(acc, w11, v11);
        }
    }

    *(float4*)(out + ((size_t)(b * kQ + q)) * kRow + h * kD + sub * 4) = acc;
}

extern "C" void kernel_launch(void* const* d_in, const int* in_sizes, int n_in,
                              void* d_out, int out_size, void* d_ws, size_t ws_size,
                              hipStream_t stream) {
    const float* value = (const float*)d_in[0];
    const float* loc   = (const float*)d_in[3];
    const float* attw  = (const float*)d_in[4];
    float* out = (float*)d_out;

    const int grid = kB * kHd * kBlksPerPair;   // 16 pairs * 680 = 10880
    msda_fwd<<<grid, 256, 0, stream>>>(value, loc, attw, out);
}